// Round 12
// baseline (432.371 us; speedup 1.0000x reference)
//
#include <hip/hip_runtime.h>
#include <stdint.h>

#define DIM 256
#define NEG_SLOPE 0.01f

#define NBLK 256            // coarse scatter blocks (1 per CU)
#define MAXK 800            // max coarse buckets (N <= 102400)
#define RPB 128             // rows per bucket
#define FCAP 6144           // fine-sort LDS staging capacity (48 KB)

typedef float    vfloat4 __attribute__((ext_vector_type(4)));
typedef _Float16 vhalf4  __attribute__((ext_vector_type(4)));
typedef _Float16 half8   __attribute__((ext_vector_type(8)));
typedef float    floatx4 __attribute__((ext_vector_type(4)));
typedef unsigned int vuint2 __attribute__((ext_vector_type(2)));

// ---------------- GEMM: h = x @ W^T + b  (fp16 MFMA, fp32 accum, fp16 out) ---------
// 128x64 tile / 256-thread block; cacheable x loads; col-tiles fastest in grid.

#define MBM 128
#define MBN 64
#define MBK 32
#define MLDP 40

__global__ __launch_bounds__(256) void gemm_xwT_kernel(
        const float* __restrict__ x, const float* __restrict__ W,
        const float* __restrict__ bias, _Float16* __restrict__ h, int M) {
    __shared__ _Float16 Ax[MBM][MLDP];
    __shared__ _Float16 Bw[MBN][MLDP];

    const int tid  = (int)threadIdx.x;
    const int row0 = blockIdx.y * MBM;
    const int col0 = blockIdx.x * MBN;
    const int wid  = tid >> 6;
    const int lane = tid & 63;
    const int wr = wid >> 1;
    const int wc = wid & 1;
    const int fr = lane & 15;
    const int fk = (lane >> 4) * 8;

    const int arow = tid >> 1;
    const int ak   = (tid & 1) * 16;
    const int wrow = tid >> 2;
    const int wk   = (tid & 3) * 8;

    floatx4 acc[4][2];
#pragma unroll
    for (int m = 0; m < 4; ++m)
#pragma unroll
        for (int n = 0; n < 2; ++n) acc[m][n] = (floatx4){0.f, 0.f, 0.f, 0.f};

    for (int kk = 0; kk < DIM; kk += MBK) {
        {
            int grow = row0 + arow;
            const float* src = &x[(size_t)grow * DIM + kk + ak];
            half8 h0, h1;
            if (grow < M) {
                vfloat4 f0 = *(const vfloat4*)(src + 0);
                vfloat4 f1 = *(const vfloat4*)(src + 4);
                vfloat4 f2 = *(const vfloat4*)(src + 8);
                vfloat4 f3 = *(const vfloat4*)(src + 12);
                h0 = (half8){(_Float16)f0.x, (_Float16)f0.y, (_Float16)f0.z, (_Float16)f0.w,
                             (_Float16)f1.x, (_Float16)f1.y, (_Float16)f1.z, (_Float16)f1.w};
                h1 = (half8){(_Float16)f2.x, (_Float16)f2.y, (_Float16)f2.z, (_Float16)f2.w,
                             (_Float16)f3.x, (_Float16)f3.y, (_Float16)f3.z, (_Float16)f3.w};
            } else {
                h0 = (half8)(_Float16)0; h1 = (half8)(_Float16)0;
            }
            *(half8*)&Ax[arow][ak]     = h0;
            *(half8*)&Ax[arow][ak + 8] = h1;
        }
        {
            const float* src = &W[(size_t)(col0 + wrow) * DIM + kk + wk];
            vfloat4 f0 = *(const vfloat4*)(src + 0);
            vfloat4 f1 = *(const vfloat4*)(src + 4);
            half8 hb = (half8){(_Float16)f0.x, (_Float16)f0.y, (_Float16)f0.z, (_Float16)f0.w,
                               (_Float16)f1.x, (_Float16)f1.y, (_Float16)f1.z, (_Float16)f1.w};
            *(half8*)&Bw[wrow][wk] = hb;
        }
        __syncthreads();

        half8 a[4], b[2];
#pragma unroll
        for (int m = 0; m < 4; ++m)
            a[m] = *(const half8*)&Ax[wr * 64 + m * 16 + fr][fk];
#pragma unroll
        for (int n = 0; n < 2; ++n)
            b[n] = *(const half8*)&Bw[wc * 32 + n * 16 + fr][fk];
#pragma unroll
        for (int m = 0; m < 4; ++m)
#pragma unroll
            for (int n = 0; n < 2; ++n)
                acc[m][n] = __builtin_amdgcn_mfma_f32_16x16x32_f16(a[m], b[n], acc[m][n], 0, 0, 0);
        __syncthreads();
    }

#pragma unroll
    for (int m = 0; m < 4; ++m) {
#pragma unroll
        for (int n = 0; n < 2; ++n) {
            int col = col0 + wc * 32 + n * 16 + fr;
            float bv = bias[col];
#pragma unroll
            for (int j = 0; j < 4; ++j) {
                int row = row0 + wr * 64 + m * 16 + (lane >> 4) * 4 + j;
                if (row < M)
                    h[(size_t)row * DIM + col] = (_Float16)(acc[m][n][j] + bv);
            }
        }
    }
}

// ---------------- shared helpers ----------------

__device__ inline int wave_incl_scan(int v) {
    const int lane = threadIdx.x & 63;
#pragma unroll
    for (int off = 1; off < 64; off <<= 1) {
        int t = __shfl_up(v, off, 64);
        if (lane >= off) v += t;
    }
    return v;
}

// ---------------- sort kernels ----------------

// per-chunk bucket histogram: hist2[k][b], bucket = row>>7
__global__ __launch_bounds__(256) void hist2_kernel(const int* __restrict__ rows,
        int* __restrict__ hist2, int E, int K, int chunk) {
    __shared__ int lh[MAXK];
    const int tid = (int)threadIdx.x;
    const int b = (int)blockIdx.x;
    for (int i = tid; i < K; i += 256) lh[i] = 0;
    __syncthreads();
    const int beg = b * chunk;
    const int end = min(beg + chunk, E);
    for (int i = beg + tid; i < end; i += 256)
        atomicAdd(&lh[__builtin_nontemporal_load(&rows[i]) >> 7], 1);
    __syncthreads();
    for (int i = tid; i < K; i += 256) hist2[i * NBLK + b] = lh[i];
}

// scanA: block k scans its NBLK=256 per-chunk counts (exclusive, in place) + total[k]
__global__ __launch_bounds__(256) void scanA_kernel(int* __restrict__ hist2,
        int* __restrict__ total, int K) {
    __shared__ int wtot[4];
    const int tid = (int)threadIdx.x;
    const int lane = tid & 63, wid = tid >> 6;
    const int k = (int)blockIdx.x;
    int* row = &hist2[k * NBLK];
    int v = row[tid];
    int incl = wave_incl_scan(v);
    if (lane == 63) wtot[wid] = incl;
    __syncthreads();
    int woff = 0;
    for (int ww = 0; ww < wid; ++ww) woff += wtot[ww];
    row[tid] = woff + incl - v;
    if (tid == 255) total[k] = woff + incl;
}

// coarse scatter; computes bucket bases from total[] in-LDS (scanB folded in)
__global__ __launch_bounds__(256) void coarse_scatter_kernel(
        const int* __restrict__ rows, const int* __restrict__ cols,
        const float* __restrict__ vals, const int* __restrict__ hist2,
        const int* __restrict__ total, vuint2* __restrict__ coarse,
        int E, int K, int chunk) {
    __shared__ int bb[MAXK];
    __shared__ int cur[MAXK];
    const int tid = (int)threadIdx.x;
    const int lane = tid & 63, wid = tid >> 6;
    const int b = (int)blockIdx.x;
    // wave 0: exclusive scan of total[] -> bb
    if (wid == 0) {
        int run = 0;
        for (int base = 0; base < K; base += 64) {
            int i = base + lane;
            int v = (i < K) ? total[i] : 0;
            int incl = wave_incl_scan(v);
            if (i < K) bb[i] = run + incl - v;
            run += __shfl(incl, 63, 64);
        }
    }
    __syncthreads();
    for (int i = tid; i < K; i += 256) cur[i] = bb[i] + hist2[i * NBLK + b];
    __syncthreads();
    const int beg = b * chunk;
    const int end = min(beg + chunk, E);
    for (int i = beg + tid; i < end; i += 256) {
        int r = __builtin_nontemporal_load(&rows[i]);
        int c = __builtin_nontemporal_load(&cols[i]);
        float v = __builtin_nontemporal_load(&vals[i]);
        int pos = atomicAdd(&cur[r >> 7], 1);
        vuint2 rec;
        rec.x = ((unsigned)(r & 127) << 18) | (unsigned)c;   // row_local(7b) | col(18b)
        rec.y = __float_as_uint(v);
        coarse[pos] = rec;
    }
}

// fine sort: LDS-staged per-bucket counting sort (single global read); emits offs[]
__global__ __launch_bounds__(256) void fine_sort_kernel(
        const vuint2* __restrict__ coarse, const int* __restrict__ total,
        vuint2* __restrict__ sorted, int* __restrict__ offs,
        int N, int E, int K) {
    __shared__ vuint2 recs[FCAP];       // 48 KB
    __shared__ int bb[MAXK];
    __shared__ int lh[RPB];
    __shared__ int wtot0;
    const int tid = (int)threadIdx.x;
    const int lane = tid & 63, wid = tid >> 6;
    const int k = (int)blockIdx.x;
    const int row0 = k * RPB;

    // wave 0: exclusive scan of total[] -> bb
    if (wid == 0) {
        int run = 0;
        for (int base = 0; base < K; base += 64) {
            int i = base + lane;
            int v = (i < K) ? total[i] : 0;
            int incl = wave_incl_scan(v);
            if (i < K) bb[i] = run + incl - v;
            run += __shfl(incl, 63, 64);
        }
    }
    if (tid < RPB) lh[tid] = 0;
    __syncthreads();
    const int beg = bb[k];
    const int end = (k + 1 < K) ? bb[k + 1] : E;
    const int cnt = end - beg;
    const bool stage = (cnt <= FCAP);

    // pass 1: histogram (+ stage records in LDS)
    if (stage) {
        for (int j = beg + tid; j < end; j += 256) {
            vuint2 rec = __builtin_nontemporal_load(&coarse[j]);
            recs[j - beg] = rec;
            atomicAdd(&lh[rec.x >> 18], 1);
        }
    } else {
        for (int j = beg + tid; j < end; j += 256)
            atomicAdd(&lh[coarse[j].x >> 18], 1);
    }
    __syncthreads();

    // scan 128 counters (2 waves)
    int v = 0, incl = 0;
    if (tid < RPB) {
        v = lh[tid];
        incl = wave_incl_scan(v);
    }
    if (tid == 63) wtot0 = incl;
    __syncthreads();
    if (tid >= 64 && tid < RPB) incl += wtot0;
    if (tid < RPB) {
        int e0 = beg + incl - v;
        lh[tid] = e0;                       // cursor
        if (row0 + tid < N) offs[row0 + tid] = e0;
    }
    __syncthreads();

    // pass 2: scatter row-sorted
    if (stage) {
        for (int idx = tid; idx < cnt; idx += 256) {
            vuint2 rec = recs[idx];
            int pos = atomicAdd(&lh[rec.x >> 18], 1);
            sorted[pos] = rec;
        }
    } else {
        for (int j = beg + tid; j < end; j += 256) {
            vuint2 rec = __builtin_nontemporal_load(&coarse[j]);
            int pos = atomicAdd(&lh[rec.x >> 18], 1);
            sorted[pos] = rec;
        }
    }
}

// ---------------- aggregation: one wave per node, 4 nodes/block, 16-deep MLP ------

__global__ __launch_bounds__(256) void agg_kernel(
        const _Float16* __restrict__ h, const vuint2* __restrict__ sorted,
        const int* __restrict__ offs, float* __restrict__ out, int N, int E) {
    const int node = blockIdx.x * 4 + ((int)threadIdx.x >> 6);
    if (node >= N) return;
    const int lane = (int)threadIdx.x & 63;
    const int beg = offs[node];
    const int end = (node + 1 < N) ? offs[node + 1] : E;

    float4 acc0 = make_float4(0.f, 0.f, 0.f, 0.f);
    float4 acc1 = make_float4(0.f, 0.f, 0.f, 0.f);

    int j = beg;
    for (; j + 15 < end; j += 16) {
        vuint2 cv[16];
        vhalf4 hv[16];
#pragma unroll
        for (int u = 0; u < 16; ++u) cv[u] = __builtin_nontemporal_load(&sorted[j + u]);
#pragma unroll
        for (int u = 0; u < 16; ++u)
            hv[u] = *(const vhalf4*)(&h[(size_t)(cv[u].x & 0x3FFFF) * DIM + lane * 4]);
#pragma unroll
        for (int u = 0; u < 16; ++u) {
            float v = __uint_as_float(cv[u].y);
            float4* a = (u & 1) ? &acc1 : &acc0;
            a->x += v * (float)hv[u].x;
            a->y += v * (float)hv[u].y;
            a->z += v * (float)hv[u].z;
            a->w += v * (float)hv[u].w;
        }
    }
    if (j + 7 < end) {
        vuint2 cv[8];
        vhalf4 hv[8];
#pragma unroll
        for (int u = 0; u < 8; ++u) cv[u] = __builtin_nontemporal_load(&sorted[j + u]);
#pragma unroll
        for (int u = 0; u < 8; ++u)
            hv[u] = *(const vhalf4*)(&h[(size_t)(cv[u].x & 0x3FFFF) * DIM + lane * 4]);
#pragma unroll
        for (int u = 0; u < 8; ++u) {
            float v = __uint_as_float(cv[u].y);
            float4* a = (u & 1) ? &acc1 : &acc0;
            a->x += v * (float)hv[u].x;
            a->y += v * (float)hv[u].y;
            a->z += v * (float)hv[u].z;
            a->w += v * (float)hv[u].w;
        }
        j += 8;
    }
    if (j + 3 < end) {
        vuint2 cv[4];
        vhalf4 hv[4];
#pragma unroll
        for (int u = 0; u < 4; ++u) cv[u] = __builtin_nontemporal_load(&sorted[j + u]);
#pragma unroll
        for (int u = 0; u < 4; ++u)
            hv[u] = *(const vhalf4*)(&h[(size_t)(cv[u].x & 0x3FFFF) * DIM + lane * 4]);
#pragma unroll
        for (int u = 0; u < 4; ++u) {
            float v = __uint_as_float(cv[u].y);
            float4* a = (u & 1) ? &acc1 : &acc0;
            a->x += v * (float)hv[u].x;
            a->y += v * (float)hv[u].y;
            a->z += v * (float)hv[u].z;
            a->w += v * (float)hv[u].w;
        }
        j += 4;
    }
    for (; j < end; ++j) {
        vuint2 cv = __builtin_nontemporal_load(&sorted[j]);
        float v = __uint_as_float(cv.y);
        vhalf4 hv = *(const vhalf4*)(&h[(size_t)(cv.x & 0x3FFFF) * DIM + lane * 4]);
        acc0.x += v * (float)hv.x; acc0.y += v * (float)hv.y;
        acc0.z += v * (float)hv.z; acc0.w += v * (float)hv.w;
    }
    vfloat4 a;
    a.x = acc0.x + acc1.x;
    a.y = acc0.y + acc1.y;
    a.z = acc0.z + acc1.z;
    a.w = acc0.w + acc1.w;
    a.x = (a.x >= 0.f) ? a.x : NEG_SLOPE * a.x;
    a.y = (a.y >= 0.f) ? a.y : NEG_SLOPE * a.y;
    a.z = (a.z >= 0.f) ? a.z : NEG_SLOPE * a.z;
    a.w = (a.w >= 0.f) ? a.w : NEG_SLOPE * a.w;
    __builtin_nontemporal_store(a, (vfloat4*)(&out[(size_t)node * DIM + lane * 4]));
}

// ---------------- fallback: atomic scatter ----------------

__global__ __launch_bounds__(256) void zero_f32_kernel(float* __restrict__ p, long long n) {
    long long i = (long long)blockIdx.x * blockDim.x + threadIdx.x;
    long long stride = (long long)gridDim.x * blockDim.x;
    for (; i < n; i += stride) p[i] = 0.0f;
}

__global__ __launch_bounds__(64) void edge_atomic_kernel(
        const int* __restrict__ rows, const int* __restrict__ cols,
        const float* __restrict__ vals, const _Float16* __restrict__ h,
        float* __restrict__ out, int E) {
    const int e = blockIdx.x;
    if (e >= E) return;
    const int lane = threadIdx.x;
    const int r = rows[e];
    const int c = cols[e];
    const float v = vals[e];
    vhalf4 hv = *(const vhalf4*)(&h[(size_t)c * DIM + lane * 4]);
    float* dst = &out[(size_t)r * DIM + lane * 4];
    atomicAdd(dst + 0, v * (float)hv.x);
    atomicAdd(dst + 1, v * (float)hv.y);
    atomicAdd(dst + 2, v * (float)hv.z);
    atomicAdd(dst + 3, v * (float)hv.w);
}

__global__ __launch_bounds__(256) void leaky_kernel(float* __restrict__ p, long long n) {
    long long i = (long long)blockIdx.x * blockDim.x + threadIdx.x;
    long long stride = (long long)gridDim.x * blockDim.x;
    for (; i < n; i += stride) {
        float v = p[i];
        p[i] = (v >= 0.f) ? v : NEG_SLOPE * v;
    }
}

// ---------------- launch ----------------

extern "C" void kernel_launch(void* const* d_in, const int* in_sizes, int n_in,
                              void* d_out, int out_size, void* d_ws, size_t ws_size,
                              hipStream_t stream) {
    const float* x    = (const float*)d_in[0];
    const int*   erow = (const int*)d_in[1];
    const int*   ecol = (const int*)d_in[2];
    const float* eval_ = (const float*)d_in[3];
    const float* Ww   = (const float*)d_in[4];
    const float* Wb   = (const float*)d_in[5];
    float* out = (float*)d_out;

    const int N = in_sizes[0] / DIM;
    const int E = in_sizes[1];
    const int K = (N + RPB - 1) / RPB;
    const int chunk = (E + NBLK - 1) / NBLK;

    // workspace layout
    char* p = (char*)d_ws;
    _Float16* h = (_Float16*)p;                 p += (size_t)N * DIM * sizeof(_Float16);
    int* hist2 = (int*)p;                       p += (size_t)K * NBLK * sizeof(int);
    int* total = (int*)p;                       p += (size_t)((K + 63) & ~63) * sizeof(int);
    int* offs = (int*)p;                        p += (size_t)N * sizeof(int);
    uintptr_t up = ((uintptr_t)p + 15) & ~(uintptr_t)15;
    vuint2* sorted = (vuint2*)up;
    size_t need_full = (size_t)((char*)sorted - (char*)d_ws) + (size_t)E * sizeof(vuint2);
    size_t need_h = (size_t)N * DIM * sizeof(_Float16);
    bool coarse_fits = ((size_t)out_size * sizeof(float)) >= (size_t)E * sizeof(vuint2);

    // col-tiles fastest so blocks sharing an x panel are dispatch-adjacent
    dim3 ggrid(DIM / MBN, (N + MBM - 1) / MBM);

    if (ws_size >= need_full && K <= MAXK && coarse_fits && N <= (1 << 18)) {
        vuint2* coarse = (vuint2*)d_out;
        hist2_kernel<<<NBLK, 256, 0, stream>>>(erow, hist2, E, K, chunk);
        scanA_kernel<<<K, 256, 0, stream>>>(hist2, total, K);
        coarse_scatter_kernel<<<NBLK, 256, 0, stream>>>(erow, ecol, eval_, hist2,
                                                        total, coarse, E, K, chunk);
        fine_sort_kernel<<<K, 256, 0, stream>>>(coarse, total, sorted, offs, N, E, K);
        gemm_xwT_kernel<<<ggrid, 256, 0, stream>>>(x, Ww, Wb, h, N);
        agg_kernel<<<(N + 3) / 4, 256, 0, stream>>>(h, sorted, offs, out, N, E);
    } else if (ws_size >= need_h) {
        gemm_xwT_kernel<<<ggrid, 256, 0, stream>>>(x, Ww, Wb, h, N);
        zero_f32_kernel<<<2048, 256, 0, stream>>>(out, (long long)N * DIM);
        edge_atomic_kernel<<<E, 64, 0, stream>>>(erow, ecol, eval_, h, out, E);
        leaky_kernel<<<2048, 256, 0, stream>>>(out, (long long)N * DIM);
    }
}

// Round 13
// 420.149 us; speedup vs baseline: 1.0291x; 1.0291x over previous
//
#include <hip/hip_runtime.h>
#include <stdint.h>

#define DIM 256
#define NEG_SLOPE 0.01f

#define NBLK 512            // coarse scatter blocks (2 per CU)
#define MAXK 400            // max coarse buckets (N <= 102400)
#define ROWS_PER_BUCKET 256

typedef float    vfloat4 __attribute__((ext_vector_type(4)));
typedef _Float16 vhalf4  __attribute__((ext_vector_type(4)));
typedef _Float16 half8   __attribute__((ext_vector_type(8)));
typedef float    floatx4 __attribute__((ext_vector_type(4)));
typedef unsigned int vuint2 __attribute__((ext_vector_type(2)));

// ---------------- GEMM: h = x @ W^T + b  (fp16 MFMA, fp32 accum, fp16 out) ---------
// 128x64 tile / 256-thread block; cacheable x loads; col-tiles fastest in grid
// (4 blocks sharing an x panel are dispatch-adjacent -> L2/L3 hits).

#define MBM 128
#define MBN 64
#define MBK 32
#define MLDP 40

__global__ __launch_bounds__(256) void gemm_xwT_kernel(
        const float* __restrict__ x, const float* __restrict__ W,
        const float* __restrict__ bias, _Float16* __restrict__ h, int M) {
    __shared__ _Float16 Ax[MBM][MLDP];
    __shared__ _Float16 Bw[MBN][MLDP];

    const int tid  = (int)threadIdx.x;
    const int row0 = blockIdx.y * MBM;
    const int col0 = blockIdx.x * MBN;
    const int wid  = tid >> 6;
    const int lane = tid & 63;
    const int wr = wid >> 1;
    const int wc = wid & 1;
    const int fr = lane & 15;
    const int fk = (lane >> 4) * 8;

    const int arow = tid >> 1;
    const int ak   = (tid & 1) * 16;
    const int wrow = tid >> 2;
    const int wk   = (tid & 3) * 8;

    floatx4 acc[4][2];
#pragma unroll
    for (int m = 0; m < 4; ++m)
#pragma unroll
        for (int n = 0; n < 2; ++n) acc[m][n] = (floatx4){0.f, 0.f, 0.f, 0.f};

    for (int kk = 0; kk < DIM; kk += MBK) {
        {
            int grow = row0 + arow;
            const float* src = &x[(size_t)grow * DIM + kk + ak];
            half8 h0, h1;
            if (grow < M) {
                vfloat4 f0 = *(const vfloat4*)(src + 0);
                vfloat4 f1 = *(const vfloat4*)(src + 4);
                vfloat4 f2 = *(const vfloat4*)(src + 8);
                vfloat4 f3 = *(const vfloat4*)(src + 12);
                h0 = (half8){(_Float16)f0.x, (_Float16)f0.y, (_Float16)f0.z, (_Float16)f0.w,
                             (_Float16)f1.x, (_Float16)f1.y, (_Float16)f1.z, (_Float16)f1.w};
                h1 = (half8){(_Float16)f2.x, (_Float16)f2.y, (_Float16)f2.z, (_Float16)f2.w,
                             (_Float16)f3.x, (_Float16)f3.y, (_Float16)f3.z, (_Float16)f3.w};
            } else {
                h0 = (half8)(_Float16)0; h1 = (half8)(_Float16)0;
            }
            *(half8*)&Ax[arow][ak]     = h0;
            *(half8*)&Ax[arow][ak + 8] = h1;
        }
        {
            const float* src = &W[(size_t)(col0 + wrow) * DIM + kk + wk];
            vfloat4 f0 = *(const vfloat4*)(src + 0);
            vfloat4 f1 = *(const vfloat4*)(src + 4);
            half8 hb = (half8){(_Float16)f0.x, (_Float16)f0.y, (_Float16)f0.z, (_Float16)f0.w,
                               (_Float16)f1.x, (_Float16)f1.y, (_Float16)f1.z, (_Float16)f1.w};
            *(half8*)&Bw[wrow][wk] = hb;
        }
        __syncthreads();

        half8 a[4], b[2];
#pragma unroll
        for (int m = 0; m < 4; ++m)
            a[m] = *(const half8*)&Ax[wr * 64 + m * 16 + fr][fk];
#pragma unroll
        for (int n = 0; n < 2; ++n)
            b[n] = *(const half8*)&Bw[wc * 32 + n * 16 + fr][fk];
#pragma unroll
        for (int m = 0; m < 4; ++m)
#pragma unroll
            for (int n = 0; n < 2; ++n)
                acc[m][n] = __builtin_amdgcn_mfma_f32_16x16x32_f16(a[m], b[n], acc[m][n], 0, 0, 0);
        __syncthreads();
    }

#pragma unroll
    for (int m = 0; m < 4; ++m) {
#pragma unroll
        for (int n = 0; n < 2; ++n) {
            int col = col0 + wc * 32 + n * 16 + fr;
            float bv = bias[col];
#pragma unroll
            for (int j = 0; j < 4; ++j) {
                int row = row0 + wr * 64 + m * 16 + (lane >> 4) * 4 + j;
                if (row < M)
                    h[(size_t)row * DIM + col] = (_Float16)(acc[m][n][j] + bv);
            }
        }
    }
}

// ---------------- shared helpers ----------------

__device__ inline int wave_incl_scan(int v) {
    const int lane = threadIdx.x & 63;
#pragma unroll
    for (int off = 1; off < 64; off <<= 1) {
        int t = __shfl_up(v, off, 64);
        if (lane >= off) v += t;
    }
    return v;
}

// ---------------- sort kernels (5-dispatch pipeline, measured-good) ----------------

__global__ __launch_bounds__(256) void hist2_kernel(const int* __restrict__ rows,
        int* __restrict__ hist2, int E, int K, int chunk) {
    __shared__ int lh[MAXK];
    const int tid = (int)threadIdx.x;
    const int b = (int)blockIdx.x;
    for (int i = tid; i < K; i += 256) lh[i] = 0;
    __syncthreads();
    const int beg = b * chunk;
    const int end = min(beg + chunk, E);
    for (int i = beg + tid; i < end; i += 256)
        atomicAdd(&lh[__builtin_nontemporal_load(&rows[i]) >> 8], 1);
    __syncthreads();
    for (int i = tid; i < K; i += 256) hist2[i * NBLK + b] = lh[i];
}

__global__ __launch_bounds__(256) void scanA_kernel(int* __restrict__ hist2,
        int* __restrict__ total, int K) {
    __shared__ int wtot[4];
    const int tid = (int)threadIdx.x;
    const int lane = tid & 63, wid = tid >> 6;
    const int k = (int)blockIdx.x;
    int* row = &hist2[k * NBLK];
    int v0 = row[tid * 2], v1 = row[tid * 2 + 1];
    int s = v0 + v1;
    int incl = wave_incl_scan(s);
    if (lane == 63) wtot[wid] = incl;
    __syncthreads();
    int woff = 0;
    for (int ww = 0; ww < wid; ++ww) woff += wtot[ww];
    int excl = woff + incl - s;
    row[tid * 2] = excl;
    row[tid * 2 + 1] = excl + v0;
    if (tid == 255) total[k] = woff + incl;
}

__global__ __launch_bounds__(64) void scanB_kernel(const int* __restrict__ total,
        int* __restrict__ bbase, int K) {
    const int lane = (int)threadIdx.x;
    int run = 0;
    for (int b = 0; b < K; b += 64) {
        int i = b + lane;
        int v = (i < K) ? total[i] : 0;
        int incl = wave_incl_scan(v);
        if (i < K) bbase[i] = run + incl - v;
        run += __shfl(incl, 63, 64);
    }
}

__global__ __launch_bounds__(256) void coarse_scatter_kernel(
        const int* __restrict__ rows, const int* __restrict__ cols,
        const float* __restrict__ vals, const int* __restrict__ hist2,
        const int* __restrict__ bbase, vuint2* __restrict__ coarse,
        int E, int K, int chunk) {
    __shared__ int cur[MAXK];
    const int tid = (int)threadIdx.x;
    const int b = (int)blockIdx.x;
    for (int i = tid; i < K; i += 256) cur[i] = bbase[i] + hist2[i * NBLK + b];
    __syncthreads();
    const int beg = b * chunk;
    const int end = min(beg + chunk, E);
    for (int i = beg + tid; i < end; i += 256) {
        int r = __builtin_nontemporal_load(&rows[i]);
        int c = __builtin_nontemporal_load(&cols[i]);
        float v = __builtin_nontemporal_load(&vals[i]);
        int pos = atomicAdd(&cur[r >> 8], 1);
        vuint2 rec;
        rec.x = ((unsigned)(r & 255) << 18) | (unsigned)c;
        rec.y = __float_as_uint(v);
        coarse[pos] = rec;
    }
}

__global__ __launch_bounds__(256) void fine_sort_kernel(
        const vuint2* __restrict__ coarse, const int* __restrict__ bbase,
        vuint2* __restrict__ sorted, int* __restrict__ offs,
        int N, int E, int K) {
    __shared__ int lh[ROWS_PER_BUCKET];
    __shared__ int wtot[4];
    const int tid = (int)threadIdx.x;
    const int lane = tid & 63, wid = tid >> 6;
    const int k = (int)blockIdx.x;
    const int row0 = k * ROWS_PER_BUCKET;
    const int beg = bbase[k];
    const int end = (k + 1 < K) ? bbase[k + 1] : E;
    lh[tid] = 0;
    __syncthreads();
    for (int j = beg + tid; j < end; j += 256)
        atomicAdd(&lh[coarse[j].x >> 18], 1);
    __syncthreads();
    int v = lh[tid];
    int incl = wave_incl_scan(v);
    if (lane == 63) wtot[wid] = incl;
    __syncthreads();
    int woff = 0;
    for (int ww = 0; ww < wid; ++ww) woff += wtot[ww];
    int excl = woff + incl - v;
    lh[tid] = beg + excl;
    if (row0 + tid < N) offs[row0 + tid] = beg + excl;
    __syncthreads();
    for (int j = beg + tid; j < end; j += 256) {
        vuint2 rec = __builtin_nontemporal_load(&coarse[j]);
        int pos = atomicAdd(&lh[rec.x >> 18], 1);
        sorted[pos] = rec;
    }
}

// ---------------- aggregation: one wave per node, 4 nodes/block, 8-deep MLP -------

__global__ __launch_bounds__(256) void agg_kernel(
        const _Float16* __restrict__ h, const vuint2* __restrict__ sorted,
        const int* __restrict__ offs, float* __restrict__ out, int N, int E) {
    const int node = blockIdx.x * 4 + ((int)threadIdx.x >> 6);
    if (node >= N) return;
    const int lane = (int)threadIdx.x & 63;
    const int beg = offs[node];
    const int end = (node + 1 < N) ? offs[node + 1] : E;

    float4 acc0 = make_float4(0.f, 0.f, 0.f, 0.f);
    float4 acc1 = make_float4(0.f, 0.f, 0.f, 0.f);

    int j = beg;
    for (; j + 7 < end; j += 8) {
        vuint2 cv[8];
        vhalf4 hv[8];
#pragma unroll
        for (int u = 0; u < 8; ++u) cv[u] = __builtin_nontemporal_load(&sorted[j + u]);
#pragma unroll
        for (int u = 0; u < 8; ++u)
            hv[u] = *(const vhalf4*)(&h[(size_t)(cv[u].x & 0x3FFFF) * DIM + lane * 4]);
#pragma unroll
        for (int u = 0; u < 8; ++u) {
            float v = __uint_as_float(cv[u].y);
            float4* a = (u & 1) ? &acc1 : &acc0;
            a->x += v * (float)hv[u].x;
            a->y += v * (float)hv[u].y;
            a->z += v * (float)hv[u].z;
            a->w += v * (float)hv[u].w;
        }
    }
    for (; j < end; ++j) {
        vuint2 cv = __builtin_nontemporal_load(&sorted[j]);
        float v = __uint_as_float(cv.y);
        vhalf4 hv = *(const vhalf4*)(&h[(size_t)(cv.x & 0x3FFFF) * DIM + lane * 4]);
        acc0.x += v * (float)hv.x; acc0.y += v * (float)hv.y;
        acc0.z += v * (float)hv.z; acc0.w += v * (float)hv.w;
    }
    vfloat4 a;
    a.x = acc0.x + acc1.x;
    a.y = acc0.y + acc1.y;
    a.z = acc0.z + acc1.z;
    a.w = acc0.w + acc1.w;
    a.x = (a.x >= 0.f) ? a.x : NEG_SLOPE * a.x;
    a.y = (a.y >= 0.f) ? a.y : NEG_SLOPE * a.y;
    a.z = (a.z >= 0.f) ? a.z : NEG_SLOPE * a.z;
    a.w = (a.w >= 0.f) ? a.w : NEG_SLOPE * a.w;
    __builtin_nontemporal_store(a, (vfloat4*)(&out[(size_t)node * DIM + lane * 4]));
}

// ---------------- fallback: atomic scatter ----------------

__global__ __launch_bounds__(256) void zero_f32_kernel(float* __restrict__ p, long long n) {
    long long i = (long long)blockIdx.x * blockDim.x + threadIdx.x;
    long long stride = (long long)gridDim.x * blockDim.x;
    for (; i < n; i += stride) p[i] = 0.0f;
}

__global__ __launch_bounds__(64) void edge_atomic_kernel(
        const int* __restrict__ rows, const int* __restrict__ cols,
        const float* __restrict__ vals, const _Float16* __restrict__ h,
        float* __restrict__ out, int E) {
    const int e = blockIdx.x;
    if (e >= E) return;
    const int lane = threadIdx.x;
    const int r = rows[e];
    const int c = cols[e];
    const float v = vals[e];
    vhalf4 hv = *(const vhalf4*)(&h[(size_t)c * DIM + lane * 4]);
    float* dst = &out[(size_t)r * DIM + lane * 4];
    atomicAdd(dst + 0, v * (float)hv.x);
    atomicAdd(dst + 1, v * (float)hv.y);
    atomicAdd(dst + 2, v * (float)hv.z);
    atomicAdd(dst + 3, v * (float)hv.w);
}

__global__ __launch_bounds__(256) void leaky_kernel(float* __restrict__ p, long long n) {
    long long i = (long long)blockIdx.x * blockDim.x + threadIdx.x;
    long long stride = (long long)gridDim.x * blockDim.x;
    for (; i < n; i += stride) {
        float v = p[i];
        p[i] = (v >= 0.f) ? v : NEG_SLOPE * v;
    }
}

// ---------------- launch ----------------

extern "C" void kernel_launch(void* const* d_in, const int* in_sizes, int n_in,
                              void* d_out, int out_size, void* d_ws, size_t ws_size,
                              hipStream_t stream) {
    const float* x    = (const float*)d_in[0];
    const int*   erow = (const int*)d_in[1];
    const int*   ecol = (const int*)d_in[2];
    const float* eval_ = (const float*)d_in[3];
    const float* Ww   = (const float*)d_in[4];
    const float* Wb   = (const float*)d_in[5];
    float* out = (float*)d_out;

    const int N = in_sizes[0] / DIM;
    const int E = in_sizes[1];
    const int K = (N + ROWS_PER_BUCKET - 1) / ROWS_PER_BUCKET;
    const int chunk = (E + NBLK - 1) / NBLK;

    // workspace layout
    char* p = (char*)d_ws;
    _Float16* h = (_Float16*)p;                 p += (size_t)N * DIM * sizeof(_Float16);
    int* hist2 = (int*)p;                       p += (size_t)K * NBLK * sizeof(int);
    int* total = (int*)p;                       p += (size_t)((K + 63) & ~63) * sizeof(int);
    int* bbase = (int*)p;                       p += (size_t)((K + 63) & ~63) * sizeof(int);
    int* offs = (int*)p;                        p += (size_t)N * sizeof(int);
    uintptr_t up = ((uintptr_t)p + 15) & ~(uintptr_t)15;
    vuint2* sorted = (vuint2*)up;
    size_t need_full = (size_t)((char*)sorted - (char*)d_ws) + (size_t)E * sizeof(vuint2);
    size_t need_h = (size_t)N * DIM * sizeof(_Float16);
    bool coarse_fits = ((size_t)out_size * sizeof(float)) >= (size_t)E * sizeof(vuint2);

    // col-tiles fastest so blocks sharing an x panel are dispatch-adjacent
    dim3 ggrid(DIM / MBN, (N + MBM - 1) / MBM);

    if (ws_size >= need_full && K <= MAXK && coarse_fits && N <= (1 << 18)) {
        vuint2* coarse = (vuint2*)d_out;
        hist2_kernel<<<NBLK, 256, 0, stream>>>(erow, hist2, E, K, chunk);
        scanA_kernel<<<K, 256, 0, stream>>>(hist2, total, K);
        scanB_kernel<<<1, 64, 0, stream>>>(total, bbase, K);
        coarse_scatter_kernel<<<NBLK, 256, 0, stream>>>(erow, ecol, eval_, hist2,
                                                        bbase, coarse, E, K, chunk);
        fine_sort_kernel<<<K, 256, 0, stream>>>(coarse, bbase, sorted, offs, N, E, K);
        gemm_xwT_kernel<<<ggrid, 256, 0, stream>>>(x, Ww, Wb, h, N);
        agg_kernel<<<(N + 3) / 4, 256, 0, stream>>>(h, sorted, offs, out, N, E);
    } else if (ws_size >= need_h) {
        gemm_xwT_kernel<<<ggrid, 256, 0, stream>>>(x, Ww, Wb, h, N);
        zero_f32_kernel<<<2048, 256, 0, stream>>>(out, (long long)N * DIM);
        edge_atomic_kernel<<<E, 64, 0, stream>>>(erow, ecol, eval_, h, out, E);
        leaky_kernel<<<2048, 256, 0, stream>>>(out, (long long)N * DIM);
    }
}